// Round 1
// baseline (359.637 us; speedup 1.0000x reference)
//
#include <hip/hip_runtime.h>

#define BATCH 1024
#define STSZ 16641
#define ATSZ 129
#define ST1SZ 16384
#define K1 33154
#define K1P 33280          // padded to 520 * 64
#define HID 512
#define ODIM 129
#define NKT 520            // K1P / 64
#define NSLICE 16

typedef __bf16 bf16;
typedef bf16 bf16x8 __attribute__((ext_vector_type(8)));
typedef float floatx4 __attribute__((ext_vector_type(4)));

typedef __attribute__((address_space(3))) unsigned int as3_uint;
typedef __attribute__((address_space(1))) unsigned int as1_uint;

__device__ __forceinline__ unsigned short f2bf(float f) {
  unsigned int u = __float_as_uint(f);
  unsigned int r = (u + 0x7FFFu + ((u >> 16) & 1u)) >> 16;  // RNE
  return (unsigned short)r;
}

__device__ __forceinline__ void gload_lds16(const unsigned short* g, unsigned short* l) {
  __builtin_amdgcn_global_load_lds((const as1_uint*)g, (as3_uint*)l, 16, 0, 0);
}

// ---------------- pack X: concat(st, at, st1) -> bf16, padded to K1P ----------------
__global__ __launch_bounds__(256) void packX(const float* __restrict__ st,
                                             const float* __restrict__ at,
                                             const float* __restrict__ st1,
                                             unsigned short* __restrict__ Xb) {
  int b = blockIdx.y;
  int p0 = (blockIdx.x * 256 + threadIdx.x) * 8;
  if (p0 >= K1P) return;
  const float* srow  = st  + (long)b * STSZ;
  const float* arow  = at  + (long)b * ATSZ;
  const float* s1row = st1 + (long)b * ST1SZ;
  unsigned short o[8];
#pragma unroll
  for (int j = 0; j < 8; ++j) {
    int p = p0 + j;
    float v;
    if (p < STSZ)            v = srow[p];
    else if (p < STSZ + ATSZ) v = arow[p - STSZ];
    else if (p < K1)         v = s1row[p - (STSZ + ATSZ)];
    else                     v = 0.0f;
    o[j] = f2bf(v);
  }
  *(uint4*)&Xb[(long)b * K1P + p0] = *(const uint4*)o;
}

// ---------------- pack W1: [K][N] fp32 -> transposed [N][K1P] bf16 ----------------
__global__ __launch_bounds__(256) void packW1(const float* __restrict__ W1,
                                              unsigned short* __restrict__ W1t) {
  __shared__ unsigned short tile[64][65];
  int k0 = blockIdx.x * 64;
  int n0 = blockIdx.y * 64;
  int tx = threadIdx.x;       // 0..63
  int ty = threadIdx.y;       // 0..3
#pragma unroll
  for (int i = 0; i < 16; ++i) {
    int k = ty + i * 4;
    int kk = k0 + k;
    float v = (kk < K1) ? W1[(long)kk * HID + n0 + tx] : 0.0f;
    tile[k][tx] = f2bf(v);
  }
  __syncthreads();
#pragma unroll
  for (int i = 0; i < 16; ++i) {
    int n = ty + i * 4;
    W1t[(long)(n0 + n) * K1P + k0 + tx] = tile[tx][n];
  }
}

// ---------------- GEMM1: Xb[1024,K1P] @ W1t[512,K1P]^T, split-K partials ----------------
__global__ __launch_bounds__(256, 2) void gemm1(const unsigned short* __restrict__ Xb,
                                                const unsigned short* __restrict__ W1t,
                                                float* __restrict__ part) {
  __shared__ __align__(16) unsigned short lA[128 * 64];
  __shared__ __align__(16) unsigned short lB[128 * 64];

  int nt = blockIdx.x;        // 0..3
  int mt = blockIdx.y;        // 0..7
  int s  = blockIdx.z;        // 0..NSLICE-1
  int t0 = s * 32 + (s < 8 ? s : 8);     // ragged: first 8 slices get 33 tiles
  int tc = 32 + (s < 8 ? 1 : 0);

  int tid = threadIdx.x;
  int wave = tid >> 6;
  int lane = tid & 63;
  int wm = (wave & 1) * 64;   // wave's M offset within tile
  int wn = (wave >> 1) * 64;  // wave's N offset within tile

  floatx4 acc[4][4] = {};

  const unsigned short* Ab = Xb  + (long)(mt * 128) * K1P;
  const unsigned short* Bb = W1t + (long)(nt * 128) * K1P;

  // staging map: chunk c = wave*4+r covers rows c*8 .. c*8+7, cols 0..63 (bf16)
  int srow = (lane >> 3);           // 0..7 within chunk
  int scol = (lane & 7) * 8;        // 0..56

  for (int it = 0; it < tc; ++it) {
    long kOff = (long)(t0 + it) * 64;
#pragma unroll
    for (int r = 0; r < 4; ++r) {
      int c = wave * 4 + r;
      int row = c * 8 + srow;
      gload_lds16(Ab + (long)row * K1P + kOff + scol, &lA[c * 512 + lane * 8]);
      gload_lds16(Bb + (long)row * K1P + kOff + scol, &lB[c * 512 + lane * 8]);
    }
    __syncthreads();
#pragma unroll
    for (int ks = 0; ks < 2; ++ks) {
      int kcol = ks * 32 + (lane >> 4) * 8;
      bf16x8 af[4], bfr[4];
#pragma unroll
      for (int i = 0; i < 4; ++i)
        af[i] = *(const bf16x8*)&lA[(wm + i * 16 + (lane & 15)) * 64 + kcol];
#pragma unroll
      for (int j = 0; j < 4; ++j)
        bfr[j] = *(const bf16x8*)&lB[(wn + j * 16 + (lane & 15)) * 64 + kcol];
#pragma unroll
      for (int i = 0; i < 4; ++i)
#pragma unroll
        for (int j = 0; j < 4; ++j)
          acc[i][j] = __builtin_amdgcn_mfma_f32_16x16x32_bf16(af[i], bfr[j], acc[i][j], 0, 0, 0);
    }
    __syncthreads();
  }

  // epilogue: C/D layout col=lane&15, row=(lane>>4)*4+reg
  float* P = part + (long)s * BATCH * HID;
  int cn = nt * 128 + wn + (lane & 15);
  int rbase = mt * 128 + wm + (lane >> 4) * 4;
#pragma unroll
  for (int i = 0; i < 4; ++i)
#pragma unroll
    for (int j = 0; j < 4; ++j)
#pragma unroll
      for (int r = 0; r < 4; ++r)
        P[(long)(rbase + i * 16 + r) * HID + cn + j * 16] = acc[i][j][r];
}

// ---------------- reduce split-K partials + bias + relu ----------------
__global__ __launch_bounds__(256) void reduceBias(const float* __restrict__ part,
                                                  const float* __restrict__ b1,
                                                  float* __restrict__ h) {
  int e = blockIdx.x * 256 + threadIdx.x;   // 0 .. 1024*512-1
  float a = b1[e & (HID - 1)];
#pragma unroll
  for (int s = 0; s < NSLICE; ++s) a += part[(long)s * BATCH * HID + e];
  h[e] = fmaxf(a, 0.0f);
}

// ---------------- GEMM2: h[1024,512] @ W2[512,129] + b2 (fp32 vector) ----------------
__global__ __launch_bounds__(256) void gemm2(const float* __restrict__ h,
                                             const float* __restrict__ W2,
                                             const float* __restrict__ b2,
                                             float* __restrict__ out) {
  __shared__ float hs[HID];
  int m = blockIdx.x;
  int t = threadIdx.x;
#pragma unroll
  for (int i = t; i < HID; i += 256) hs[i] = h[(long)m * HID + i];
  __syncthreads();
  if (t < ODIM) {
    float a = b2[t];
#pragma unroll 8
    for (int k = 0; k < HID; ++k) a += hs[k] * W2[k * ODIM + t];
    out[(long)m * ODIM + t] = a;
  }
}

extern "C" void kernel_launch(void* const* d_in, const int* in_sizes, int n_in,
                              void* d_out, int out_size, void* d_ws, size_t ws_size,
                              hipStream_t stream) {
  const float* st  = (const float*)d_in[0];
  const float* at  = (const float*)d_in[1];
  const float* st1 = (const float*)d_in[2];
  const float* W1  = (const float*)d_in[3];
  const float* b1  = (const float*)d_in[4];
  const float* W2  = (const float*)d_in[5];
  const float* b2  = (const float*)d_in[6];
  float* out = (float*)d_out;

  char* ws = (char*)d_ws;
  unsigned short* Xb  = (unsigned short*)ws;                                   // 68,157,440 B
  unsigned short* W1t = (unsigned short*)(ws + (size_t)BATCH * K1P * 2);       // 34,078,720 B
  float* part = (float*)(ws + (size_t)BATCH * K1P * 2 + (size_t)HID * K1P * 2);
  float* h    = part + (size_t)NSLICE * BATCH * HID;

  packX<<<dim3((K1P + 2047) / 2048, BATCH), 256, 0, stream>>>(st, at, st1, Xb);
  packW1<<<dim3(NKT, HID / 64), dim3(64, 4), 0, stream>>>(W1, W1t);
  gemm1<<<dim3(4, 8, NSLICE), 256, 0, stream>>>(Xb, W1t, part);
  reduceBias<<<dim3(BATCH * HID / 256), 256, 0, stream>>>(part, b1, h);
  gemm2<<<dim3(BATCH), 256, 0, stream>>>(h, W2, b2, out);
}

// Round 3
// 346.394 us; speedup vs baseline: 1.0382x; 1.0382x over previous
//
#include <hip/hip_runtime.h>

#define BATCH 1024
#define STSZ 16641
#define ATSZ 129
#define ST1SZ 16384
#define K1 33154
#define K1P 33280          // padded to 520 * 64
#define HID 512
#define ODIM 129
#define NKT 520            // K1P / 64
#define NSLICE 16

typedef __bf16 bf16;
typedef bf16 bf16x8 __attribute__((ext_vector_type(8)));
typedef float floatx4 __attribute__((ext_vector_type(4)));

typedef __attribute__((address_space(3))) unsigned int as3_uint;
typedef __attribute__((address_space(1))) unsigned int as1_uint;

__device__ __forceinline__ unsigned short f2bf(float f) {
  unsigned int u = __float_as_uint(f);
  unsigned int r = (u + 0x7FFFu + ((u >> 16) & 1u)) >> 16;  // RNE
  return (unsigned short)r;
}

__device__ __forceinline__ void gload_lds16(const unsigned short* g, unsigned short* l) {
  __builtin_amdgcn_global_load_lds((const as1_uint*)g, (as3_uint*)l, 16, 0, 0);
}

// ---------------- pack X: concat(st, at, st1) -> bf16, padded to K1P ----------------
// stride-1 per lane: every global load is a fully-coalesced 256B/wave transaction.
__global__ __launch_bounds__(256) void packX(const float* __restrict__ st,
                                             const float* __restrict__ at,
                                             const float* __restrict__ st1,
                                             unsigned short* __restrict__ Xb) {
  int b = blockIdx.y;
  int base = blockIdx.x * 2048 + threadIdx.x;
  const float* srow  = st  + (long)b * STSZ;
  const float* arow  = at  + (long)b * ATSZ;
  const float* s1row = st1 + (long)b * ST1SZ;
  unsigned short* xrow = Xb + (long)b * K1P;
#pragma unroll
  for (int u = 0; u < 8; ++u) {
    int col = base + u * 256;
    if (col >= K1P) break;
    float v;
    if (col < STSZ)              v = srow[col];
    else if (col < STSZ + ATSZ)  v = arow[col - STSZ];
    else if (col < K1)           v = s1row[col - (STSZ + ATSZ)];
    else                         v = 0.0f;
    xrow[col] = f2bf(v);
  }
}

// ---------------- pack W1: [K][N] fp32 -> transposed [N][K1P] bf16 ----------------
// float4 reads (16B/lane), LDS transpose, ushort4 packed stores. FLAT 256-thread block.
__global__ __launch_bounds__(256) void packW1(const float* __restrict__ W1,
                                              unsigned short* __restrict__ W1t) {
  __shared__ unsigned short tile[64][72];   // padded row stride
  int k0 = blockIdx.x * 64;
  int n0 = blockIdx.y * 64;
  int tid = threadIdx.x;        // 0..255 (flat)
  int nt = (tid & 15) * 4;      // n within tile, 0..60 step 4
  int kr = tid >> 4;            // 0..15
#pragma unroll
  for (int p = 0; p < 4; ++p) {
    int k = p * 16 + kr;
    int kk = k0 + k;
    float4 v = make_float4(0.f, 0.f, 0.f, 0.f);
    if (kk < K1) v = *(const float4*)&W1[(long)kk * HID + n0 + nt];
    unsigned short o[4] = { f2bf(v.x), f2bf(v.y), f2bf(v.z), f2bf(v.w) };
    *(ushort4*)&tile[k][nt] = *(const ushort4*)o;
  }
  __syncthreads();
  int kt = (tid & 15) * 4;      // k within tile, step 4
  int nr = tid >> 4;            // 0..15
#pragma unroll
  for (int p = 0; p < 4; ++p) {
    int n = p * 16 + nr;
    unsigned short o[4] = { tile[kt][n], tile[kt + 1][n], tile[kt + 2][n], tile[kt + 3][n] };
    *(ushort4*)&W1t[(long)(n0 + n) * K1P + k0 + kt] = *(const ushort4*)o;
  }
}

// ---------------- GEMM1: Xb[1024,K1P] @ W1t[512,K1P]^T, split-K partials ----------------
__global__ __launch_bounds__(256, 2) void gemm1(const unsigned short* __restrict__ Xb,
                                                const unsigned short* __restrict__ W1t,
                                                float* __restrict__ part) {
  __shared__ __align__(16) unsigned short lA[128 * 64];
  __shared__ __align__(16) unsigned short lB[128 * 64];

  int nt = blockIdx.x;        // 0..3
  int mt = blockIdx.y;        // 0..7
  int s  = blockIdx.z;        // 0..NSLICE-1
  int t0 = s * 32 + (s < 8 ? s : 8);     // ragged: first 8 slices get 33 tiles
  int tc = 32 + (s < 8 ? 1 : 0);

  int tid = threadIdx.x;
  int wave = tid >> 6;
  int lane = tid & 63;
  int wm = (wave & 1) * 64;   // wave's M offset within tile
  int wn = (wave >> 1) * 64;  // wave's N offset within tile

  floatx4 acc[4][4] = {};

  const unsigned short* Ab = Xb  + (long)(mt * 128) * K1P;
  const unsigned short* Bb = W1t + (long)(nt * 128) * K1P;

  // staging map: chunk c = wave*4+r covers rows c*8 .. c*8+7, cols 0..63 (bf16)
  int srow = (lane >> 3);           // 0..7 within chunk
  int scol = (lane & 7) * 8;        // 0..56

  for (int it = 0; it < tc; ++it) {
    long kOff = (long)(t0 + it) * 64;
#pragma unroll
    for (int r = 0; r < 4; ++r) {
      int c = wave * 4 + r;
      int row = c * 8 + srow;
      gload_lds16(Ab + (long)row * K1P + kOff + scol, &lA[c * 512 + lane * 8]);
      gload_lds16(Bb + (long)row * K1P + kOff + scol, &lB[c * 512 + lane * 8]);
    }
    __syncthreads();
#pragma unroll
    for (int ks = 0; ks < 2; ++ks) {
      int kcol = ks * 32 + (lane >> 4) * 8;
      bf16x8 af[4], bfr[4];
#pragma unroll
      for (int i = 0; i < 4; ++i)
        af[i] = *(const bf16x8*)&lA[(wm + i * 16 + (lane & 15)) * 64 + kcol];
#pragma unroll
      for (int j = 0; j < 4; ++j)
        bfr[j] = *(const bf16x8*)&lB[(wn + j * 16 + (lane & 15)) * 64 + kcol];
#pragma unroll
      for (int i = 0; i < 4; ++i)
#pragma unroll
        for (int j = 0; j < 4; ++j)
          acc[i][j] = __builtin_amdgcn_mfma_f32_16x16x32_bf16(af[i], bfr[j], acc[i][j], 0, 0, 0);
    }
    __syncthreads();
  }

  // epilogue: C/D layout col=lane&15, row=(lane>>4)*4+reg
  float* P = part + (long)s * BATCH * HID;
  int cn = nt * 128 + wn + (lane & 15);
  int rbase = mt * 128 + wm + (lane >> 4) * 4;
#pragma unroll
  for (int i = 0; i < 4; ++i)
#pragma unroll
    for (int j = 0; j < 4; ++j)
#pragma unroll
      for (int r = 0; r < 4; ++r)
        P[(long)(rbase + i * 16 + r) * HID + cn + j * 16] = acc[i][j][r];
}

// ---------------- reduce split-K partials + bias + relu ----------------
__global__ __launch_bounds__(256) void reduceBias(const float* __restrict__ part,
                                                  const float* __restrict__ b1,
                                                  float* __restrict__ h) {
  int e = blockIdx.x * 256 + threadIdx.x;   // 0 .. 1024*512-1
  float a = b1[e & (HID - 1)];
#pragma unroll
  for (int s = 0; s < NSLICE; ++s) a += part[(long)s * BATCH * HID + e];
  h[e] = fmaxf(a, 0.0f);
}

// ---------------- GEMM2: h[1024,512] @ W2[512,129] + b2 (fp32 vector) ----------------
__global__ __launch_bounds__(256) void gemm2(const float* __restrict__ h,
                                             const float* __restrict__ W2,
                                             const float* __restrict__ b2,
                                             float* __restrict__ out) {
  __shared__ float hs[HID];
  int m = blockIdx.x;
  int t = threadIdx.x;
#pragma unroll
  for (int i = t; i < HID; i += 256) hs[i] = h[(long)m * HID + i];
  __syncthreads();
  if (t < ODIM) {
    float a = b2[t];
#pragma unroll 8
    for (int k = 0; k < HID; ++k) a += hs[k] * W2[k * ODIM + t];
    out[(long)m * ODIM + t] = a;
  }
}

extern "C" void kernel_launch(void* const* d_in, const int* in_sizes, int n_in,
                              void* d_out, int out_size, void* d_ws, size_t ws_size,
                              hipStream_t stream) {
  const float* st  = (const float*)d_in[0];
  const float* at  = (const float*)d_in[1];
  const float* st1 = (const float*)d_in[2];
  const float* W1  = (const float*)d_in[3];
  const float* b1  = (const float*)d_in[4];
  const float* W2  = (const float*)d_in[5];
  const float* b2  = (const float*)d_in[6];
  float* out = (float*)d_out;

  char* ws = (char*)d_ws;
  unsigned short* Xb  = (unsigned short*)ws;                                   // 68,157,440 B
  unsigned short* W1t = (unsigned short*)(ws + (size_t)BATCH * K1P * 2);       // 34,078,720 B
  float* part = (float*)(ws + (size_t)BATCH * K1P * 2 + (size_t)HID * K1P * 2);
  float* h    = part + (size_t)NSLICE * BATCH * HID;

  packX<<<dim3((K1P + 2047) / 2048, BATCH), 256, 0, stream>>>(st, at, st1, Xb);
  packW1<<<dim3(NKT, HID / 64), 256, 0, stream>>>(W1, W1t);
  gemm1<<<dim3(4, 8, NSLICE), 256, 0, stream>>>(Xb, W1t, part);
  reduceBias<<<dim3(BATCH * HID / 256), 256, 0, stream>>>(part, b1, h);
  gemm2<<<dim3(BATCH), 256, 0, stream>>>(h, W2, b2, out);
}

// Round 4
// 329.291 us; speedup vs baseline: 1.0922x; 1.0519x over previous
//
#include <hip/hip_runtime.h>

#define BATCH 1024
#define STSZ 16641
#define ATSZ 129
#define ST1SZ 16384
#define K1 33154
#define K1P 33280          // padded to 520 * 64
#define HID 512
#define ODIM 129
#define NKT 520            // K1P / 64
#define NSLICE 16

typedef __bf16 bf16;
typedef bf16 bf16x8 __attribute__((ext_vector_type(8)));
typedef float floatx4 __attribute__((ext_vector_type(4)));
typedef float f32x4u __attribute__((ext_vector_type(4), aligned(4)));  // 4B-aligned vector load

typedef __attribute__((address_space(3))) unsigned int as3_uint;
typedef __attribute__((address_space(1))) unsigned int as1_uint;

__device__ __forceinline__ unsigned short f2bf(float f) {
  unsigned int u = __float_as_uint(f);
  unsigned int r = (u + 0x7FFFu + ((u >> 16) & 1u)) >> 16;  // RNE
  return (unsigned short)r;
}

__device__ __forceinline__ void gload_lds16(const unsigned short* g, unsigned short* l) {
  __builtin_amdgcn_global_load_lds((const as1_uint*)g, (as3_uint*)l, 16, 0, 0);
}

// ---------------- pack X: concat(st, at, st1) -> bf16, padded to K1P ----------------
// v3: one unaligned-ok float4 load + one ushort4 store per thread, straight-line.
// Wave-uniform segment branches except 3 boundary groups per row.
__global__ __launch_bounds__(256) void packX(const float* __restrict__ st,
                                             const float* __restrict__ at,
                                             const float* __restrict__ st1,
                                             unsigned short* __restrict__ Xb) {
  int b = blockIdx.y;
  int g = blockIdx.x * 256 + threadIdx.x;    // group of 4 cols
  if (g >= K1P / 4) return;
  int col = g * 4;
  const float* srow  = st  + (long)b * STSZ;
  const float* arow  = at  + (long)b * ATSZ;
  const float* s1row = st1 + (long)b * ST1SZ;

  float4 v;
  if (col + 3 < STSZ) {
    f32x4u t = *(const f32x4u*)(srow + col);
    v = make_float4(t.x, t.y, t.z, t.w);
  } else if (col >= STSZ + ATSZ && col + 3 < K1) {
    f32x4u t = *(const f32x4u*)(s1row + (col - (STSZ + ATSZ)));
    v = make_float4(t.x, t.y, t.z, t.w);
  } else if (col >= STSZ && col + 3 < STSZ + ATSZ) {
    f32x4u t = *(const f32x4u*)(arow + (col - STSZ));
    v = make_float4(t.x, t.y, t.z, t.w);
  } else if (col >= K1) {
    v = make_float4(0.f, 0.f, 0.f, 0.f);
  } else {
    // boundary groups (3 per row): scalar per element
    float e[4];
#pragma unroll
    for (int j = 0; j < 4; ++j) {
      int p = col + j;
      if (p < STSZ)                 e[j] = srow[p];
      else if (p < STSZ + ATSZ)     e[j] = arow[p - STSZ];
      else if (p < K1)              e[j] = s1row[p - (STSZ + ATSZ)];
      else                          e[j] = 0.f;
    }
    v = make_float4(e[0], e[1], e[2], e[3]);
  }
  unsigned short o[4] = { f2bf(v.x), f2bf(v.y), f2bf(v.z), f2bf(v.w) };
  *(ushort4*)&Xb[(long)b * K1P + col] = *(const ushort4*)o;
}

// ---------------- pack W1: [K][N] fp32 -> transposed [N][K1P] bf16 ----------------
// float4 reads (16B/lane), LDS transpose, ushort4 packed stores. FLAT 256-thread block.
__global__ __launch_bounds__(256) void packW1(const float* __restrict__ W1,
                                              unsigned short* __restrict__ W1t) {
  __shared__ unsigned short tile[64][72];   // padded row stride
  int k0 = blockIdx.x * 64;
  int n0 = blockIdx.y * 64;
  int tid = threadIdx.x;        // 0..255 (flat)
  int nt = (tid & 15) * 4;      // n within tile, 0..60 step 4
  int kr = tid >> 4;            // 0..15
#pragma unroll
  for (int p = 0; p < 4; ++p) {
    int k = p * 16 + kr;
    int kk = k0 + k;
    float4 v = make_float4(0.f, 0.f, 0.f, 0.f);
    if (kk < K1) v = *(const float4*)&W1[(long)kk * HID + n0 + nt];
    unsigned short o[4] = { f2bf(v.x), f2bf(v.y), f2bf(v.z), f2bf(v.w) };
    *(ushort4*)&tile[k][nt] = *(const ushort4*)o;
  }
  __syncthreads();
  int kt = (tid & 15) * 4;      // k within tile, step 4
  int nr = tid >> 4;            // 0..15
#pragma unroll
  for (int p = 0; p < 4; ++p) {
    int n = p * 16 + nr;
    unsigned short o[4] = { tile[kt][n], tile[kt + 1][n], tile[kt + 2][n], tile[kt + 3][n] };
    *(ushort4*)&W1t[(long)(n0 + n) * K1P + k0 + kt] = *(const ushort4*)o;
  }
}

// ---------------- GEMM1: Xb[1024,K1P] @ W1t[512,K1P]^T, split-K partials ----------------
__global__ __launch_bounds__(256, 2) void gemm1(const unsigned short* __restrict__ Xb,
                                                const unsigned short* __restrict__ W1t,
                                                float* __restrict__ part) {
  __shared__ __align__(16) unsigned short lA[128 * 64];
  __shared__ __align__(16) unsigned short lB[128 * 64];

  int nt = blockIdx.x;        // 0..3
  int mt = blockIdx.y;        // 0..7
  int s  = blockIdx.z;        // 0..NSLICE-1
  int t0 = s * 32 + (s < 8 ? s : 8);     // ragged: first 8 slices get 33 tiles
  int tc = 32 + (s < 8 ? 1 : 0);

  int tid = threadIdx.x;
  int wave = tid >> 6;
  int lane = tid & 63;
  int wm = (wave & 1) * 64;   // wave's M offset within tile
  int wn = (wave >> 1) * 64;  // wave's N offset within tile

  floatx4 acc[4][4] = {};

  const unsigned short* Ab = Xb  + (long)(mt * 128) * K1P;
  const unsigned short* Bb = W1t + (long)(nt * 128) * K1P;

  // staging map: chunk c = wave*4+r covers rows c*8 .. c*8+7, cols 0..63 (bf16)
  int srow = (lane >> 3);           // 0..7 within chunk
  int scol = (lane & 7) * 8;        // 0..56

  for (int it = 0; it < tc; ++it) {
    long kOff = (long)(t0 + it) * 64;
#pragma unroll
    for (int r = 0; r < 4; ++r) {
      int c = wave * 4 + r;
      int row = c * 8 + srow;
      gload_lds16(Ab + (long)row * K1P + kOff + scol, &lA[c * 512 + lane * 8]);
      gload_lds16(Bb + (long)row * K1P + kOff + scol, &lB[c * 512 + lane * 8]);
    }
    __syncthreads();
#pragma unroll
    for (int ks = 0; ks < 2; ++ks) {
      int kcol = ks * 32 + (lane >> 4) * 8;
      bf16x8 af[4], bfr[4];
#pragma unroll
      for (int i = 0; i < 4; ++i)
        af[i] = *(const bf16x8*)&lA[(wm + i * 16 + (lane & 15)) * 64 + kcol];
#pragma unroll
      for (int j = 0; j < 4; ++j)
        bfr[j] = *(const bf16x8*)&lB[(wn + j * 16 + (lane & 15)) * 64 + kcol];
#pragma unroll
      for (int i = 0; i < 4; ++i)
#pragma unroll
        for (int j = 0; j < 4; ++j)
          acc[i][j] = __builtin_amdgcn_mfma_f32_16x16x32_bf16(af[i], bfr[j], acc[i][j], 0, 0, 0);
    }
    __syncthreads();
  }

  // epilogue: C/D layout col=lane&15, row=(lane>>4)*4+reg
  float* P = part + (long)s * BATCH * HID;
  int cn = nt * 128 + wn + (lane & 15);
  int rbase = mt * 128 + wm + (lane >> 4) * 4;
#pragma unroll
  for (int i = 0; i < 4; ++i)
#pragma unroll
    for (int j = 0; j < 4; ++j)
#pragma unroll
      for (int r = 0; r < 4; ++r)
        P[(long)(rbase + i * 16 + r) * HID + cn + j * 16] = acc[i][j][r];
}

// ---------------- reduce split-K partials + bias + relu ----------------
__global__ __launch_bounds__(256) void reduceBias(const float* __restrict__ part,
                                                  const float* __restrict__ b1,
                                                  float* __restrict__ h) {
  int e = blockIdx.x * 256 + threadIdx.x;   // 0 .. 1024*512-1
  float a = b1[e & (HID - 1)];
#pragma unroll
  for (int s = 0; s < NSLICE; ++s) a += part[(long)s * BATCH * HID + e];
  h[e] = fmaxf(a, 0.0f);
}

// ---------------- GEMM2: h[1024,512] @ W2[512,129] + b2 (fp32 vector) ----------------
__global__ __launch_bounds__(256) void gemm2(const float* __restrict__ h,
                                             const float* __restrict__ W2,
                                             const float* __restrict__ b2,
                                             float* __restrict__ out) {
  __shared__ float hs[HID];
  int m = blockIdx.x;
  int t = threadIdx.x;
#pragma unroll
  for (int i = t; i < HID; i += 256) hs[i] = h[(long)m * HID + i];
  __syncthreads();
  if (t < ODIM) {
    float a = b2[t];
#pragma unroll 8
    for (int k = 0; k < HID; ++k) a += hs[k] * W2[k * ODIM + t];
    out[(long)m * ODIM + t] = a;
  }
}

extern "C" void kernel_launch(void* const* d_in, const int* in_sizes, int n_in,
                              void* d_out, int out_size, void* d_ws, size_t ws_size,
                              hipStream_t stream) {
  const float* st  = (const float*)d_in[0];
  const float* at  = (const float*)d_in[1];
  const float* st1 = (const float*)d_in[2];
  const float* W1  = (const float*)d_in[3];
  const float* b1  = (const float*)d_in[4];
  const float* W2  = (const float*)d_in[5];
  const float* b2  = (const float*)d_in[6];
  float* out = (float*)d_out;

  char* ws = (char*)d_ws;
  unsigned short* Xb  = (unsigned short*)ws;                                   // 68,157,440 B
  unsigned short* W1t = (unsigned short*)(ws + (size_t)BATCH * K1P * 2);       // 34,078,720 B
  float* part = (float*)(ws + (size_t)BATCH * K1P * 2 + (size_t)HID * K1P * 2);
  float* h    = part + (size_t)NSLICE * BATCH * HID;

  packX<<<dim3((K1P / 4 + 255) / 256, BATCH), 256, 0, stream>>>(st, at, st1, Xb);
  packW1<<<dim3(NKT, HID / 64), 256, 0, stream>>>(W1, W1t);
  gemm1<<<dim3(4, 8, NSLICE), 256, 0, stream>>>(Xb, W1t, part);
  reduceBias<<<dim3(BATCH * HID / 256), 256, 0, stream>>>(part, b1, h);
  gemm2<<<dim3(BATCH), 256, 0, stream>>>(h, W2, b2, out);
}

// Round 5
// 326.750 us; speedup vs baseline: 1.1006x; 1.0078x over previous
//
#include <hip/hip_runtime.h>

#define BATCH 1024
#define STSZ 16641
#define ATSZ 129
#define ST1SZ 16384
#define K1 33154
#define K1P 33280          // padded to 520 * 64
#define HID 512
#define ODIM 129
#define NKT 520            // K1P / 64
#define NSLICE 32          // 4 blocks/CU residency

typedef __bf16 bf16;
typedef bf16 bf16x8 __attribute__((ext_vector_type(8)));
typedef float floatx4 __attribute__((ext_vector_type(4)));
typedef float f32x4u __attribute__((ext_vector_type(4), aligned(4)));  // 4B-aligned vector load

typedef __attribute__((address_space(3))) unsigned int as3_uint;
typedef __attribute__((address_space(1))) unsigned int as1_uint;

__device__ __forceinline__ unsigned short f2bf(float f) {
  unsigned int u = __float_as_uint(f);
  unsigned int r = (u + 0x7FFFu + ((u >> 16) & 1u)) >> 16;  // RNE
  return (unsigned short)r;
}
__device__ __forceinline__ float bf2f(unsigned short s) {
  unsigned int u = ((unsigned int)s) << 16;
  return __uint_as_float(u);
}

__device__ __forceinline__ void gload_lds16(const unsigned short* g, unsigned short* l) {
  __builtin_amdgcn_global_load_lds((const as1_uint*)g, (as3_uint*)l, 16, 0, 0);
}

// ---------------- pack X: concat(st, at, st1) -> bf16, padded to K1P ----------------
__global__ __launch_bounds__(256) void packX(const float* __restrict__ st,
                                             const float* __restrict__ at,
                                             const float* __restrict__ st1,
                                             unsigned short* __restrict__ Xb) {
  int b = blockIdx.y;
  int g = blockIdx.x * 256 + threadIdx.x;    // group of 4 cols
  if (g >= K1P / 4) return;
  int col = g * 4;
  const float* srow  = st  + (long)b * STSZ;
  const float* arow  = at  + (long)b * ATSZ;
  const float* s1row = st1 + (long)b * ST1SZ;

  float4 v;
  if (col + 3 < STSZ) {
    f32x4u t = *(const f32x4u*)(srow + col);
    v = make_float4(t.x, t.y, t.z, t.w);
  } else if (col >= STSZ + ATSZ && col + 3 < K1) {
    f32x4u t = *(const f32x4u*)(s1row + (col - (STSZ + ATSZ)));
    v = make_float4(t.x, t.y, t.z, t.w);
  } else if (col >= STSZ && col + 3 < STSZ + ATSZ) {
    f32x4u t = *(const f32x4u*)(arow + (col - STSZ));
    v = make_float4(t.x, t.y, t.z, t.w);
  } else if (col >= K1) {
    v = make_float4(0.f, 0.f, 0.f, 0.f);
  } else {
    float e[4];
#pragma unroll
    for (int j = 0; j < 4; ++j) {
      int p = col + j;
      if (p < STSZ)                 e[j] = srow[p];
      else if (p < STSZ + ATSZ)     e[j] = arow[p - STSZ];
      else if (p < K1)              e[j] = s1row[p - (STSZ + ATSZ)];
      else                          e[j] = 0.f;
    }
    v = make_float4(e[0], e[1], e[2], e[3]);
  }
  unsigned short o[4] = { f2bf(v.x), f2bf(v.y), f2bf(v.z), f2bf(v.w) };
  *(ushort4*)&Xb[(long)b * K1P + col] = *(const ushort4*)o;
}

// ---------------- pack W1: [K][N] fp32 -> transposed [N][K1P] bf16 ----------------
__global__ __launch_bounds__(256) void packW1(const float* __restrict__ W1,
                                              unsigned short* __restrict__ W1t) {
  __shared__ unsigned short tile[64][72];   // padded row stride
  int k0 = blockIdx.x * 64;
  int n0 = blockIdx.y * 64;
  int tid = threadIdx.x;        // 0..255 (flat)
  int nt = (tid & 15) * 4;      // n within tile, 0..60 step 4
  int kr = tid >> 4;            // 0..15
#pragma unroll
  for (int p = 0; p < 4; ++p) {
    int k = p * 16 + kr;
    int kk = k0 + k;
    float4 v = make_float4(0.f, 0.f, 0.f, 0.f);
    if (kk < K1) v = *(const float4*)&W1[(long)kk * HID + n0 + nt];
    unsigned short o[4] = { f2bf(v.x), f2bf(v.y), f2bf(v.z), f2bf(v.w) };
    *(ushort4*)&tile[k][nt] = *(const ushort4*)o;
  }
  __syncthreads();
  int kt = (tid & 15) * 4;      // k within tile, step 4
  int nr = tid >> 4;            // 0..15
#pragma unroll
  for (int p = 0; p < 4; ++p) {
    int n = p * 16 + nr;
    unsigned short o[4] = { tile[kt][n], tile[kt + 1][n], tile[kt + 2][n], tile[kt + 3][n] };
    *(ushort4*)&W1t[(long)(n0 + n) * K1P + k0 + kt] = *(const ushort4*)o;
  }
}

// ---------------- GEMM1: Xb[1024,K1P] @ W1t[512,K1P]^T, split-K bf16 partials ----------------
// LDS layout with XOR bank swizzle: chunk c holds rows c*8..c*8+7; lane stores
// global (row = c*8 + (lane>>3), colgrp = (lane&7)^(lane>>3)) at LDS lane*16B.
// Reader of (row, colgrp q): short idx = row*64 + 8*(q ^ (row&7)).
__global__ __launch_bounds__(256, 2) void gemm1(const unsigned short* __restrict__ Xb,
                                                const unsigned short* __restrict__ W1t,
                                                unsigned short* __restrict__ part) {
  __shared__ __align__(16) unsigned short lA[128 * 64];
  __shared__ __align__(16) unsigned short lB[128 * 64];

  int nt = blockIdx.x;        // 0..3
  int mt = blockIdx.y;        // 0..7
  int s  = blockIdx.z;        // 0..NSLICE-1
  int t0 = s * 16 + (s < 8 ? s : 8);     // ragged: 520 = 8*17 + 24*16
  int tc = 16 + (s < 8 ? 1 : 0);

  int tid = threadIdx.x;
  int wave = tid >> 6;
  int lane = tid & 63;
  int wm = (wave & 1) * 64;   // wave's M offset within tile
  int wn = (wave >> 1) * 64;  // wave's N offset within tile

  floatx4 acc[4][4] = {};

  const unsigned short* Ab = Xb  + (long)(mt * 128) * K1P;
  const unsigned short* Bb = W1t + (long)(nt * 128) * K1P;

  int srow = lane >> 3;                 // 0..7 within chunk
  int scol = ((lane & 7) ^ srow) * 8;   // swizzled col group, 0..56

  int sr = lane & 7;                    // (fragment row) & 7 — wave-uniform per lane

  for (int it = 0; it < tc; ++it) {
    long kOff = (long)(t0 + it) * 64;
#pragma unroll
    for (int r = 0; r < 4; ++r) {
      int c = wave * 4 + r;
      int row = c * 8 + srow;
      gload_lds16(Ab + (long)row * K1P + kOff + scol, &lA[c * 512 + lane * 8]);
      gload_lds16(Bb + (long)row * K1P + kOff + scol, &lB[c * 512 + lane * 8]);
    }
    __syncthreads();
#pragma unroll
    for (int ks = 0; ks < 2; ++ks) {
      int q = ks * 4 + (lane >> 4);               // col group 0..7
      int kidx = ((q ^ sr)) * 8;                  // swizzled short offset within row
      bf16x8 af[4], bfr[4];
#pragma unroll
      for (int i = 0; i < 4; ++i)
        af[i] = *(const bf16x8*)&lA[(wm + i * 16 + (lane & 15)) * 64 + kidx];
#pragma unroll
      for (int j = 0; j < 4; ++j)
        bfr[j] = *(const bf16x8*)&lB[(wn + j * 16 + (lane & 15)) * 64 + kidx];
#pragma unroll
      for (int i = 0; i < 4; ++i)
#pragma unroll
        for (int j = 0; j < 4; ++j)
          acc[i][j] = __builtin_amdgcn_mfma_f32_16x16x32_bf16(af[i], bfr[j], acc[i][j], 0, 0, 0);
    }
    __syncthreads();
  }

  // epilogue: C/D layout col=lane&15, row=(lane>>4)*4+reg ; bf16 partials
  unsigned short* P = part + (long)s * BATCH * HID;
  int cn = nt * 128 + wn + (lane & 15);
  int rbase = mt * 128 + wm + (lane >> 4) * 4;
#pragma unroll
  for (int i = 0; i < 4; ++i)
#pragma unroll
    for (int j = 0; j < 4; ++j)
#pragma unroll
      for (int r = 0; r < 4; ++r)
        P[(long)(rbase + i * 16 + r) * HID + cn + j * 16] = f2bf(acc[i][j][r]);
}

// ---------------- reduce split-K bf16 partials + bias + relu ----------------
__global__ __launch_bounds__(256) void reduceBias(const unsigned short* __restrict__ part,
                                                  const float* __restrict__ b1,
                                                  float* __restrict__ h) {
  int e4 = blockIdx.x * 256 + threadIdx.x;        // group of 4 elements
  float4 a = ((const float4*)b1)[e4 & (HID / 4 - 1)];
#pragma unroll
  for (int s = 0; s < NSLICE; ++s) {
    ushort4 p = ((const ushort4*)part)[(long)s * (BATCH * HID / 4) + e4];
    a.x += bf2f(p.x); a.y += bf2f(p.y); a.z += bf2f(p.z); a.w += bf2f(p.w);
  }
  a.x = fmaxf(a.x, 0.f); a.y = fmaxf(a.y, 0.f);
  a.z = fmaxf(a.z, 0.f); a.w = fmaxf(a.w, 0.f);
  ((float4*)h)[e4] = a;
}

// ---------------- GEMM2: h[1024,512] @ W2[512,129] + b2 (fp32 vector) ----------------
__global__ __launch_bounds__(256) void gemm2(const float* __restrict__ h,
                                             const float* __restrict__ W2,
                                             const float* __restrict__ b2,
                                             float* __restrict__ out) {
  __shared__ float hs[HID];
  int m = blockIdx.x;
  int t = threadIdx.x;
#pragma unroll
  for (int i = t; i < HID; i += 256) hs[i] = h[(long)m * HID + i];
  __syncthreads();
  if (t < ODIM) {
    float a = b2[t];
#pragma unroll 8
    for (int k = 0; k < HID; ++k) a += hs[k] * W2[k * ODIM + t];
    out[(long)m * ODIM + t] = a;
  }
}

extern "C" void kernel_launch(void* const* d_in, const int* in_sizes, int n_in,
                              void* d_out, int out_size, void* d_ws, size_t ws_size,
                              hipStream_t stream) {
  const float* st  = (const float*)d_in[0];
  const float* at  = (const float*)d_in[1];
  const float* st1 = (const float*)d_in[2];
  const float* W1  = (const float*)d_in[3];
  const float* b1  = (const float*)d_in[4];
  const float* W2  = (const float*)d_in[5];
  const float* b2  = (const float*)d_in[6];
  float* out = (float*)d_out;

  char* ws = (char*)d_ws;
  unsigned short* Xb   = (unsigned short*)ws;                                  // 68,157,440 B
  unsigned short* W1t  = (unsigned short*)(ws + (size_t)BATCH * K1P * 2);      // 34,078,720 B
  unsigned short* part = (unsigned short*)(ws + (size_t)BATCH * K1P * 2 + (size_t)HID * K1P * 2); // 33,554,432 B
  float* h = (float*)(ws + (size_t)BATCH * K1P * 2 + (size_t)HID * K1P * 2
                      + (size_t)NSLICE * BATCH * HID * 2);                     // 2,097,152 B

  packX<<<dim3((K1P / 4 + 255) / 256, BATCH), 256, 0, stream>>>(st, at, st1, Xb);
  packW1<<<dim3(NKT, HID / 64), 256, 0, stream>>>(W1, W1t);
  gemm1<<<dim3(4, 8, NSLICE), 256, 0, stream>>>(Xb, W1t, part);
  reduceBias<<<dim3(BATCH * HID / 4 / 256), 256, 0, stream>>>(part, b1, h);
  gemm2<<<dim3(BATCH), 256, 0, stream>>>(h, W2, b2, out);
}